// Round 1
// baseline (208.098 us; speedup 1.0000x reference)
//
#include <hip/hip_runtime.h>
#include <stdint.h>

#define N_SPK 2048
#define M_UTT 16
#define D_EMB 512
#define NM (N_SPK * M_UTT)

typedef __attribute__((ext_vector_type(8))) short bf16x8;
typedef __attribute__((ext_vector_type(4))) float f32x4;

// round-to-nearest-even float -> bf16 bits
__device__ __forceinline__ short f2bf(float x) {
    uint32_t u = __float_as_uint(x);
    uint32_t r = (u + 0x7fffu + ((u >> 16) & 1u)) >> 16;
    return (short)r;
}

__device__ __forceinline__ void async_copy16(const short* g, short* l) {
    __builtin_amdgcn_global_load_lds(
        (const __attribute__((address_space(1))) unsigned int*)g,
        (__attribute__((address_space(3))) unsigned int*)l,
        16, 0, 0);
}

// ---------------------------------------------------------------------------
// Kernel A: per-speaker prep. One block (256 thr) per speaker.
//  - ssum = sum over 16 utterances         -> LDS
//  - Cn[spk] = bf16(normalize(ssum/16))    (||C|| clamped at eps)
//  - vn[j]   = bf16(normalize(v_j))
//  - dterm[j]= w * cos(ssum - v_j, v_j) + b   (fp32, exact leave-one-out sim)
// ---------------------------------------------------------------------------
__global__ __launch_bounds__(256) void prep_kernel(
    const float* __restrict__ V, const float* __restrict__ wp,
    const float* __restrict__ bp, short* __restrict__ Cn,
    short* __restrict__ vn, float* __restrict__ dterm)
{
    const int spk  = blockIdx.x;
    const int tid  = threadIdx.x;
    const int wave = tid >> 6, lane = tid & 63;
    const float* vb = V + (size_t)spk * (M_UTT * D_EMB);

    __shared__ float4 ssum4[D_EMB / 4];
    __shared__ float  wred[4];

    // ---- phase 1: per-dim sum over utterances + centroid norm ----
    const float2* vb2 = (const float2*)vb;
    float2 s = make_float2(0.f, 0.f);
#pragma unroll
    for (int m = 0; m < M_UTT; ++m) {
        float2 t = vb2[m * (D_EMB / 2) + tid];
        s.x += t.x; s.y += t.y;
    }
    ((float2*)ssum4)[tid] = s;
    float cpart = s.x * s.x + s.y * s.y;
#pragma unroll
    for (int off = 32; off > 0; off >>= 1) cpart += __shfl_xor(cpart, off);
    if (lane == 0) wred[wave] = cpart;
    __syncthreads();

    const float cn2    = wred[0] + wred[1] + wred[2] + wred[3];
    const float cnorm  = sqrtf(cn2) * (1.0f / M_UTT);          // ||C||
    const float cscale = 1.0f / (M_UTT * fmaxf(cnorm, 1e-8f)); // ssum*cscale = Cn
    {
        short2 o;
        o.x = f2bf(s.x * cscale);
        o.y = f2bf(s.y * cscale);
        ((short2*)(Cn + (size_t)spk * D_EMB))[tid] = o;
    }

    // ---- phase 2: per-utterance norms, leave-one-out sim, vn ----
    const float wgt = *wp, bsc = *bp;
    const float4* vb4 = (const float4*)vb;
    const float4* ss4 = (const float4*)ssum4;
#pragma unroll
    for (int mi = 0; mi < 4; ++mi) {
        const int m = wave * 4 + mi;
        float4 p0 = vb4[m * (D_EMB / 4) + lane * 2];
        float4 p1 = vb4[m * (D_EMB / 4) + lane * 2 + 1];
        float4 q0 = ss4[lane * 2];
        float4 q1 = ss4[lane * 2 + 1];
        float pv[8] = {p0.x, p0.y, p0.z, p0.w, p1.x, p1.y, p1.z, p1.w};
        float qv[8] = {q0.x, q0.y, q0.z, q0.w, q1.x, q1.y, q1.z, q1.w};
        float vv = 0.f, cv = 0.f, cc = 0.f;
#pragma unroll
        for (int k = 0; k < 8; ++k) {
            float c = qv[k] - pv[k];   // (ssum - v)_d  (C_min up to /15)
            vv += pv[k] * pv[k];
            cv += c * pv[k];
            cc += c * c;
        }
#pragma unroll
        for (int off = 32; off > 0; off >>= 1) {
            vv += __shfl_xor(vv, off);
            cv += __shfl_xor(cv, off);
            cc += __shfl_xor(cc, off);
        }
        const float nv = sqrtf(vv);
        const float nc = sqrtf(cc);
        const float dv = fmaxf(nv, 1e-8f);
        const float dc = fmaxf(nc * (1.0f / (M_UTT - 1)), 1e-8f) * (M_UTT - 1);
        const float S  = cv / (dc * dv);
        if (lane == 0) dterm[spk * M_UTT + m] = wgt * S + bsc;

        const float inv = 1.0f / dv;
        bf16x8 o;
        o[0] = f2bf(pv[0] * inv); o[1] = f2bf(pv[1] * inv);
        o[2] = f2bf(pv[2] * inv); o[3] = f2bf(pv[3] * inv);
        o[4] = f2bf(pv[4] * inv); o[5] = f2bf(pv[5] * inv);
        o[6] = f2bf(pv[6] * inv); o[7] = f2bf(pv[7] * inv);
        *(bf16x8*)(vn + ((size_t)(spk * M_UTT + m)) * D_EMB + lane * 8) = o;
    }
}

// ---------------------------------------------------------------------------
// Kernel B: S = Cn @ vn^T fused with exp(w*S+b), same-speaker masking, and
// column reduction into colsum[NM].  128x128 tile, BK=64, 4 waves of 64x64,
// 16x16x32 bf16 MFMA, global_load_lds width-16 staging (m97 structure).
// ---------------------------------------------------------------------------
__global__ __launch_bounds__(256) void gemm_kernel(
    const short* __restrict__ Cn, const short* __restrict__ vn,
    const float* __restrict__ wp, const float* __restrict__ bp,
    float* __restrict__ colsum)
{
    __shared__ short As[128 * 64];
    __shared__ short Bs[128 * 64];
    __shared__ float csum[128];

    const int tid  = threadIdx.x;
    const int wave = tid >> 6, lane = tid & 63;
    const int bx = blockIdx.x;   // col tile: utterances   [0,256)
    const int by = blockIdx.y;   // row tile: speakers     [0,16)
    const float wgt = *wp, bsc = *bp;

    if (tid < 128) csum[tid] = 0.f;   // first k-loop barrier makes this visible

    // staging geometry: each wave stages 32 rows (4 issues x 8 rows x 16B/lane)
    const int strow = wave * 32 + (lane >> 3);
    const int stcol = (lane & 7) * 8;
    const short* Abase = Cn + (size_t)(by * 128 + strow) * D_EMB + stcol;
    const short* Bbase = vn + (size_t)(bx * 128 + strow) * D_EMB + stcol;
    short* AsW = &As[(wave * 32) * 64];
    short* BsW = &Bs[(wave * 32) * 64];

    // compute geometry: 2x2 wave grid, each wave 64x64 = 4x4 MFMA tiles
    const int wm = wave & 1, wn = wave >> 1;
    const int l16 = lane & 15, quad = lane >> 4;
    const short* ArdBase = &As[(wm * 64 + l16) * 64 + quad * 8];
    const short* BrdBase = &Bs[(wn * 64 + l16) * 64 + quad * 8];

    f32x4 acc[4][4];
    const f32x4 z = {0.f, 0.f, 0.f, 0.f};
#pragma unroll
    for (int i = 0; i < 4; ++i)
#pragma unroll
        for (int j = 0; j < 4; ++j) acc[i][j] = z;

    for (int kk = 0; kk < D_EMB / 64; ++kk) {
        const int k0 = kk * 64;
        __syncthreads();
#pragma unroll
        for (int i = 0; i < 4; ++i) {
            async_copy16(Abase + (size_t)(i * 8) * D_EMB + k0, AsW + i * 8 * 64);
            async_copy16(Bbase + (size_t)(i * 8) * D_EMB + k0, BsW + i * 8 * 64);
        }
        __syncthreads();
#pragma unroll
        for (int ks = 0; ks < 64; ks += 32) {
            bf16x8 af[4], bfj[4];
#pragma unroll
            for (int i = 0; i < 4; ++i) af[i] = *(const bf16x8*)(ArdBase + i * 16 * 64 + ks);
#pragma unroll
            for (int j = 0; j < 4; ++j) bfj[j] = *(const bf16x8*)(BrdBase + j * 16 * 64 + ks);
#pragma unroll
            for (int i = 0; i < 4; ++i)
#pragma unroll
                for (int j = 0; j < 4; ++j)
                    acc[i][j] = __builtin_amdgcn_mfma_f32_16x16x32_bf16(
                        af[i], bfj[j], acc[i][j], 0, 0, 0);
        }
    }

    // epilogue: e = exp(w*S+b), zero same-speaker entries, reduce over rows.
    // D layout: row m = quad*4 + r (speaker), col n = l16 (utterance).
    const int rowg0 = by * 128 + wm * 64 + quad * 4;
    const int colg0 = bx * 128 + wn * 64 + l16;
#pragma unroll
    for (int j = 0; j < 4; ++j) {
        const int colg = colg0 + j * 16;
        const int cspk = colg >> 4;       // speaker owning this column
        float p = 0.f;
#pragma unroll
        for (int i = 0; i < 4; ++i) {
            const int rowg = rowg0 + i * 16;
#pragma unroll
            for (int r = 0; r < 4; ++r) {
                float e = __expf(wgt * acc[i][j][r] + bsc);
                p += (rowg + r == cspk) ? 0.f : e;
            }
        }
        p += __shfl_xor(p, 16);
        p += __shfl_xor(p, 32);
        if (quad == 0) atomicAdd(&csum[wn * 64 + j * 16 + l16], p);
    }
    __syncthreads();
    if (tid < 128) atomicAdd(&colsum[bx * 128 + tid], csum[tid]);
}

// ---------------------------------------------------------------------------
// Kernel C: L_j = -dterm_j + log(colsum_j + exp(dterm_j)); sum -> out[0]
// ---------------------------------------------------------------------------
__global__ __launch_bounds__(256) void finish_kernel(
    const float* __restrict__ dterm, const float* __restrict__ colsum,
    float* __restrict__ out)
{
    const int idx = blockIdx.x * 256 + threadIdx.x;
    const int stride = gridDim.x * 256;
    float local = 0.f;
    for (int j = idx; j < NM; j += stride) {
        float t = dterm[j];
        local += logf(colsum[j] + __expf(t)) - t;
    }
#pragma unroll
    for (int off = 32; off > 0; off >>= 1) local += __shfl_xor(local, off);
    __shared__ float wr[4];
    const int wave = threadIdx.x >> 6, lane = threadIdx.x & 63;
    if (lane == 0) wr[wave] = local;
    __syncthreads();
    if (threadIdx.x == 0) atomicAdd(out, wr[0] + wr[1] + wr[2] + wr[3]);
}

extern "C" void kernel_launch(void* const* d_in, const int* in_sizes, int n_in,
                              void* d_out, int out_size, void* d_ws, size_t ws_size,
                              hipStream_t stream) {
    const float* V  = (const float*)d_in[0];
    const float* wp = (const float*)d_in[1];
    const float* bp = (const float*)d_in[2];
    // d_in[3] = speakers (2048) — dims hardcoded to match the fixed harness shapes

    char*  ws     = (char*)d_ws;
    short* Cn     = (short*)ws;                              //  2 MB  [2048][512] bf16
    short* vn     = (short*)(ws + ((size_t)2 << 20));        // 32 MB  [32768][512] bf16
    float* dterm  = (float*)(ws + ((size_t)34 << 20));       // 128 KB [32768]
    float* colsum = dterm + NM;                              // 128 KB [32768]
    float* out    = (float*)d_out;

    hipMemsetAsync(colsum, 0, NM * sizeof(float), stream);
    hipMemsetAsync(out, 0, sizeof(float), stream);

    prep_kernel<<<N_SPK, 256, 0, stream>>>(V, wp, bp, Cn, vn, dterm);
    gemm_kernel<<<dim3(NM / 128, N_SPK / 128), 256, 0, stream>>>(Cn, vn, wp, bp, colsum);
    finish_kernel<<<64, 256, 0, stream>>>(dterm, colsum, out);
}

// Round 2
// 202.986 us; speedup vs baseline: 1.0252x; 1.0252x over previous
//
#include <hip/hip_runtime.h>
#include <stdint.h>

#define N_SPK 2048
#define M_UTT 16
#define D_EMB 512
#define NM (N_SPK * M_UTT)

typedef __attribute__((ext_vector_type(8))) short bf16x8;
typedef __attribute__((ext_vector_type(4))) float f32x4;

// round-to-nearest-even float -> bf16 bits
__device__ __forceinline__ short f2bf(float x) {
    uint32_t u = __float_as_uint(x);
    uint32_t r = (u + 0x7fffu + ((u >> 16) & 1u)) >> 16;
    return (short)r;
}

__device__ __forceinline__ void async_copy16(const short* g, short* l) {
    __builtin_amdgcn_global_load_lds(
        (const __attribute__((address_space(1))) unsigned int*)g,
        (__attribute__((address_space(3))) unsigned int*)l,
        16, 0, 0);
}

// ---------------------------------------------------------------------------
// Kernel A: per-speaker prep. One block (128 thr = 2 waves) per speaker.
// Thread t owns dims [4t, 4t+4). Single HBM read pass (re-reads are L1/L2 hot).
//  - ssum (float4/thread, register-resident)
//  - sv[m] = <ssum, v_m>, vv[m] = ||v_m||^2  via batched LDS row-reduction
//  - cc[m] = ||ssum||^2 - 2 sv + vv ; cv[m] = sv - vv  (algebraic identities)
//  - dterm[j] = w * cos(C_min_j, v_j) + b   (fp32 exact)
//  - Cn = bf16(normalize(ssum/16)), vn = bf16(normalize(v))
// ---------------------------------------------------------------------------
__global__ __launch_bounds__(128) void prep_kernel(
    const float* __restrict__ V, const float* __restrict__ wp,
    const float* __restrict__ bp, short* __restrict__ Cn,
    short* __restrict__ vn, float* __restrict__ dterm)
{
    const int spk  = blockIdx.x;
    const int t    = threadIdx.x;
    const int wave = t >> 6, lane = t & 63;
    const float4* vb = (const float4*)(V + (size_t)spk * (M_UTT * D_EMB)); // [16][128]

    __shared__ __align__(16) float red[32][132];  // rows 0..15 sv, 16..31 vv (+4 pad)
    __shared__ float red2[32];
    __shared__ float invnv[M_UTT];
    __shared__ float wred[2];

    // ---- pass 1: ssum over utterances (local per-dim, no reduction needed) ----
    float4 ss = make_float4(0.f, 0.f, 0.f, 0.f);
#pragma unroll
    for (int m = 0; m < M_UTT; ++m) {
        float4 p = vb[m * 128 + t];
        ss.x += p.x; ss.y += p.y; ss.z += p.z; ss.w += p.w;
    }
    // ||ssum||^2 butterfly (2 waves -> wred)
    float cnp = ss.x * ss.x + ss.y * ss.y + ss.z * ss.z + ss.w * ss.w;
#pragma unroll
    for (int off = 32; off > 0; off >>= 1) cnp += __shfl_xor(cnp, off);
    if (lane == 0) wred[wave] = cnp;

    // ---- pass 2: per-utterance partials -> LDS (loads are L1/L2 hot) ----
#pragma unroll
    for (int m = 0; m < M_UTT; ++m) {
        float4 p = vb[m * 128 + t];
        red[m][t]          = ss.x * p.x + ss.y * p.y + ss.z * p.z + ss.w * p.w; // sv part
        red[m + M_UTT][t]  = p.x * p.x + p.y * p.y + p.z * p.z + p.w * p.w;     // vv part
    }
    __syncthreads();
    const float cn2 = wred[0] + wred[1];

    // ---- batched row reduction: 4 threads per row, 8 float4 each ----
    {
        const int r = t >> 2, s = t & 3;
        const float4* rp = (const float4*)red;   // row stride = 33 float4
        float4 a = make_float4(0.f, 0.f, 0.f, 0.f);
#pragma unroll
        for (int k = 0; k < 8; ++k) {
            float4 q = rp[r * 33 + s + 4 * k];
            a.x += q.x; a.y += q.y; a.z += q.z; a.w += q.w;
        }
        float v1 = (a.x + a.y) + (a.z + a.w);
        v1 += __shfl_xor(v1, 1);
        v1 += __shfl_xor(v1, 2);
        if (s == 0) red2[r] = v1;
    }
    __syncthreads();

    // ---- per-utterance scalars ----
    if (t < M_UTT) {
        const float sv = red2[t], vv = red2[t + M_UTT];
        const float cc = cn2 - 2.f * sv + vv;      // ||ssum - v||^2
        const float cv = sv - vv;                  // <ssum - v, v>
        const float dc = fmaxf(sqrtf(fmaxf(cc, 0.f)) * (1.f / (M_UTT - 1)), 1e-8f) * (M_UTT - 1);
        const float dv = fmaxf(sqrtf(vv), 1e-8f);
        const float S  = cv / (dc * dv);
        dterm[spk * M_UTT + t] = (*wp) * S + (*bp);
        invnv[t] = 1.f / dv;
    }
    __syncthreads();

    // ---- outputs ----
    const float cscale = 1.f / (M_UTT * fmaxf(sqrtf(cn2) * (1.f / M_UTT), 1e-8f));
    {
        short4 o;
        o.x = f2bf(ss.x * cscale); o.y = f2bf(ss.y * cscale);
        o.z = f2bf(ss.z * cscale); o.w = f2bf(ss.w * cscale);
        ((short4*)(Cn + (size_t)spk * D_EMB))[t] = o;
    }
#pragma unroll
    for (int m = 0; m < M_UTT; ++m) {
        float4 p = vb[m * 128 + t];
        const float iv = invnv[m];
        short4 o;
        o.x = f2bf(p.x * iv); o.y = f2bf(p.y * iv);
        o.z = f2bf(p.z * iv); o.w = f2bf(p.w * iv);
        ((short4*)(vn + ((size_t)(spk * M_UTT + m)) * D_EMB))[t] = o;
    }
}

// ---------------------------------------------------------------------------
// Kernel B: S = Cn @ vn^T fused with exp(w*S+b), same-speaker masking, and
// column reduction into colsum[NM].  128x128 tile, BK=64, 4 waves of 64x64,
// 16x16x32 bf16 MFMA, global_load_lds width-16 staging.
// LDS columns XOR-swizzled (granule g' = g ^ (row&7)) to kill the 16-way
// bank conflicts of the 128B-row layout. Since global_load_lds places lane i
// at base+16*i, the swizzle is applied to the *global source column* per lane.
// ---------------------------------------------------------------------------
__global__ __launch_bounds__(256) void gemm_kernel(
    const short* __restrict__ Cn, const short* __restrict__ vn,
    const float* __restrict__ wp, const float* __restrict__ bp,
    float* __restrict__ colsum)
{
    __shared__ short As[128 * 64];
    __shared__ short Bs[128 * 64];
    __shared__ float csum[128];

    const int tid  = threadIdx.x;
    const int wave = tid >> 6, lane = tid & 63;
    const int by = blockIdx.x;   // row tile: speakers    [0,16)   (fast-varying)
    const int bx = blockIdx.y;   // col tile: utterances  [0,256)
    const float wgt = *wp, bsc = *bp;

    if (tid < 128) csum[tid] = 0.f;   // first k-loop barrier makes this visible

    // staging: each wave stages 32 rows (4 issues x 8 rows x 16B/lane).
    // source column granule = (lane&7) ^ (row&7); row&7 == (lane>>3)&7.
    const int strow = wave * 32 + (lane >> 3);
    const int stcol = (((lane & 7) ^ ((lane >> 3) & 7))) * 8;
    const short* Abase = Cn + (size_t)(by * 128 + strow) * D_EMB + stcol;
    const short* Bbase = vn + (size_t)(bx * 128 + strow) * D_EMB + stcol;
    short* AsW = &As[(wave * 32) * 64];
    short* BsW = &Bs[(wave * 32) * 64];

    // compute geometry: 2x2 wave grid, each wave 64x64 = 4x4 MFMA tiles
    const int wm = wave & 1, wn = wave >> 1;
    const int l16 = lane & 15, quad = lane >> 4;
    const int rb = l16 & 7;
    const int go0 = (quad ^ rb) * 8;         // ks=0  granule offset (shorts)
    const int go1 = ((quad + 4) ^ rb) * 8;   // ks=32 granule offset
    const short* ArdBase = &As[(wm * 64 + l16) * 64];
    const short* BrdBase = &Bs[(wn * 64 + l16) * 64];

    f32x4 acc[4][4];
    const f32x4 z = {0.f, 0.f, 0.f, 0.f};
#pragma unroll
    for (int i = 0; i < 4; ++i)
#pragma unroll
        for (int j = 0; j < 4; ++j) acc[i][j] = z;

    for (int kk = 0; kk < D_EMB / 64; ++kk) {
        const int k0 = kk * 64;
        __syncthreads();
#pragma unroll
        for (int i = 0; i < 4; ++i) {
            async_copy16(Abase + (size_t)(i * 8) * D_EMB + k0, AsW + i * 8 * 64);
            async_copy16(Bbase + (size_t)(i * 8) * D_EMB + k0, BsW + i * 8 * 64);
        }
        __syncthreads();
#pragma unroll
        for (int ks = 0; ks < 2; ++ks) {
            const int go = ks ? go1 : go0;
            bf16x8 af[4], bfj[4];
#pragma unroll
            for (int i = 0; i < 4; ++i) af[i] = *(const bf16x8*)(ArdBase + i * 16 * 64 + go);
#pragma unroll
            for (int j = 0; j < 4; ++j) bfj[j] = *(const bf16x8*)(BrdBase + j * 16 * 64 + go);
#pragma unroll
            for (int i = 0; i < 4; ++i)
#pragma unroll
                for (int j = 0; j < 4; ++j)
                    acc[i][j] = __builtin_amdgcn_mfma_f32_16x16x32_bf16(
                        af[i], bfj[j], acc[i][j], 0, 0, 0);
        }
    }

    // epilogue: e = exp(w*S+b), zero same-speaker entries, reduce over rows.
    // D layout: row m = quad*4 + r (speaker), col n = l16 (utterance).
    const int rowg0 = by * 128 + wm * 64 + quad * 4;
    const int colg0 = bx * 128 + wn * 64 + l16;
#pragma unroll
    for (int j = 0; j < 4; ++j) {
        const int colg = colg0 + j * 16;
        const int cspk = colg >> 4;       // speaker owning this column
        float p = 0.f;
#pragma unroll
        for (int i = 0; i < 4; ++i) {
            const int rowg = rowg0 + i * 16;
#pragma unroll
            for (int r = 0; r < 4; ++r) {
                float e = __expf(wgt * acc[i][j][r] + bsc);
                p += (rowg + r == cspk) ? 0.f : e;
            }
        }
        p += __shfl_xor(p, 16);
        p += __shfl_xor(p, 32);
        if (quad == 0) atomicAdd(&csum[wn * 64 + j * 16 + l16], p);
    }
    __syncthreads();
    if (tid < 128) atomicAdd(&colsum[bx * 128 + tid], csum[tid]);
}

// ---------------------------------------------------------------------------
// Kernel C: L_j = -dterm_j + log(colsum_j + exp(dterm_j)); sum -> out[0]
// ---------------------------------------------------------------------------
__global__ __launch_bounds__(256) void finish_kernel(
    const float* __restrict__ dterm, const float* __restrict__ colsum,
    float* __restrict__ out)
{
    const int idx = blockIdx.x * 256 + threadIdx.x;
    const int stride = gridDim.x * 256;
    float local = 0.f;
    for (int j = idx; j < NM; j += stride) {
        float t = dterm[j];
        local += logf(colsum[j] + __expf(t)) - t;
    }
#pragma unroll
    for (int off = 32; off > 0; off >>= 1) local += __shfl_xor(local, off);
    __shared__ float wr[4];
    const int wave = threadIdx.x >> 6, lane = threadIdx.x & 63;
    if (lane == 0) wr[wave] = local;
    __syncthreads();
    if (threadIdx.x == 0) atomicAdd(out, wr[0] + wr[1] + wr[2] + wr[3]);
}

extern "C" void kernel_launch(void* const* d_in, const int* in_sizes, int n_in,
                              void* d_out, int out_size, void* d_ws, size_t ws_size,
                              hipStream_t stream) {
    const float* V  = (const float*)d_in[0];
    const float* wp = (const float*)d_in[1];
    const float* bp = (const float*)d_in[2];

    char*  ws     = (char*)d_ws;
    short* Cn     = (short*)ws;                              //  2 MB  [2048][512] bf16
    short* vn     = (short*)(ws + ((size_t)2 << 20));        // 32 MB  [32768][512] bf16
    float* dterm  = (float*)(ws + ((size_t)34 << 20));       // 128 KB [32768]
    float* colsum = dterm + NM;                              // 128 KB [32768]
    float* out    = (float*)d_out;

    hipMemsetAsync(colsum, 0, NM * sizeof(float), stream);
    hipMemsetAsync(out, 0, sizeof(float), stream);

    prep_kernel<<<N_SPK, 128, 0, stream>>>(V, wp, bp, Cn, vn, dterm);
    gemm_kernel<<<dim3(N_SPK / 128, NM / 128), 256, 0, stream>>>(Cn, vn, wp, bp, colsum);
    finish_kernel<<<64, 256, 0, stream>>>(dterm, colsum, out);
}

// Round 3
// 185.202 us; speedup vs baseline: 1.1236x; 1.0960x over previous
//
#include <hip/hip_runtime.h>
#include <stdint.h>

#define N_SPK 2048
#define M_UTT 16
#define D_EMB 512
#define NM (N_SPK * M_UTT)

typedef __attribute__((ext_vector_type(8))) short bf16x8;
typedef __attribute__((ext_vector_type(4))) float f32x4;

// round-to-nearest-even float -> bf16 bits
__device__ __forceinline__ short f2bf(float x) {
    uint32_t u = __float_as_uint(x);
    uint32_t r = (u + 0x7fffu + ((u >> 16) & 1u)) >> 16;
    return (short)r;
}

__device__ __forceinline__ void async_copy16(const short* g, short* l) {
    __builtin_amdgcn_global_load_lds(
        (const __attribute__((address_space(1))) unsigned int*)g,
        (__attribute__((address_space(3))) unsigned int*)l,
        16, 0, 0);
}

// ---------------------------------------------------------------------------
// Kernel A: per-speaker prep, SINGLE global pass, register-resident.
// One block (128 thr = 2 waves) per speaker; thread t owns dims [4t,4t+4).
// All 16 utterance float4s live in registers (64 VGPRs); ssum, the
// sv/vv partials, and all outputs (Cn, vn, dterm) derive from them with one
// LDS batched reduction. Also folds the colsum/out zeroing (graph memset
// nodes removed).
// ---------------------------------------------------------------------------
__global__ __launch_bounds__(128) void prep_kernel(
    const float* __restrict__ V, const float* __restrict__ wp,
    const float* __restrict__ bp, short* __restrict__ Cn,
    short* __restrict__ vn, float* __restrict__ dterm,
    float* __restrict__ colsum, float* __restrict__ out)
{
    const int spk  = blockIdx.x;
    const int t    = threadIdx.x;
    const int wave = t >> 6, lane = t & 63;
    const float4* vb = (const float4*)(V + (size_t)spk * (M_UTT * D_EMB)); // [16][128]

    __shared__ __align__(16) float red[32][132];  // rows 0..15 sv, 16..31 vv (+4 pad)
    __shared__ float red2[32];
    __shared__ float invnv[M_UTT];
    __shared__ float wred[2];

    // folded memsets: zero colsum (2048 blocks cover 32768 with first 256) + out
    if (spk < 256) colsum[spk * 128 + t] = 0.f;
    if (spk == 0 && t == 0) out[0] = 0.f;

    // ---- single global read pass: everything register-resident ----
    float4 p[M_UTT];
#pragma unroll
    for (int m = 0; m < M_UTT; ++m) p[m] = vb[m * 128 + t];

    float4 ss = make_float4(0.f, 0.f, 0.f, 0.f);
#pragma unroll
    for (int m = 0; m < M_UTT; ++m) {
        ss.x += p[m].x; ss.y += p[m].y; ss.z += p[m].z; ss.w += p[m].w;
    }

    // ||ssum||^2 butterfly (2 waves -> wred)
    float cnp = ss.x * ss.x + ss.y * ss.y + ss.z * ss.z + ss.w * ss.w;
#pragma unroll
    for (int off = 32; off > 0; off >>= 1) cnp += __shfl_xor(cnp, off);
    if (lane == 0) wred[wave] = cnp;

    // per-utterance partials -> LDS (from registers, no global re-read)
#pragma unroll
    for (int m = 0; m < M_UTT; ++m) {
        red[m][t]         = ss.x * p[m].x + ss.y * p[m].y + ss.z * p[m].z + ss.w * p[m].w;
        red[m + M_UTT][t] = p[m].x * p[m].x + p[m].y * p[m].y + p[m].z * p[m].z + p[m].w * p[m].w;
    }
    __syncthreads();
    const float cn2 = wred[0] + wred[1];

    // ---- batched row reduction: 4 threads per row, 8 float4 each ----
    {
        const int r = t >> 2, s = t & 3;
        const float4* rp = (const float4*)red;   // row stride = 33 float4
        float4 a = make_float4(0.f, 0.f, 0.f, 0.f);
#pragma unroll
        for (int k = 0; k < 8; ++k) {
            float4 q = rp[r * 33 + s + 4 * k];
            a.x += q.x; a.y += q.y; a.z += q.z; a.w += q.w;
        }
        float v1 = (a.x + a.y) + (a.z + a.w);
        v1 += __shfl_xor(v1, 1);
        v1 += __shfl_xor(v1, 2);
        if (s == 0) red2[r] = v1;
    }
    __syncthreads();

    // ---- per-utterance scalars ----
    if (t < M_UTT) {
        const float sv = red2[t], vv = red2[t + M_UTT];
        const float cc = cn2 - 2.f * sv + vv;      // ||ssum - v||^2
        const float cv = sv - vv;                  // <ssum - v, v>
        const float dc = fmaxf(sqrtf(fmaxf(cc, 0.f)) * (1.f / (M_UTT - 1)), 1e-8f) * (M_UTT - 1);
        const float dv = fmaxf(sqrtf(vv), 1e-8f);
        const float S  = cv / (dc * dv);
        dterm[spk * M_UTT + t] = (*wp) * S + (*bp);
        invnv[t] = 1.f / dv;
    }
    __syncthreads();

    // ---- outputs (from registers) ----
    const float cscale = 1.f / (M_UTT * fmaxf(sqrtf(cn2) * (1.f / M_UTT), 1e-8f));
    {
        short4 o;
        o.x = f2bf(ss.x * cscale); o.y = f2bf(ss.y * cscale);
        o.z = f2bf(ss.z * cscale); o.w = f2bf(ss.w * cscale);
        ((short4*)(Cn + (size_t)spk * D_EMB))[t] = o;
    }
#pragma unroll
    for (int m = 0; m < M_UTT; ++m) {
        const float iv = invnv[m];
        short4 o;
        o.x = f2bf(p[m].x * iv); o.y = f2bf(p[m].y * iv);
        o.z = f2bf(p[m].z * iv); o.w = f2bf(p[m].w * iv);
        ((short4*)(vn + ((size_t)(spk * M_UTT + m)) * D_EMB))[t] = o;
    }
}

// ---------------------------------------------------------------------------
// Kernel B: S = Cn @ vn^T fused with exp(w*S+b), same-speaker masking, and
// column reduction into colsum[NM].  128x128 tile, BK=64, 4 waves of 64x64,
// 16x16x32 bf16 MFMA, global_load_lds width-16 staging.
// LDS columns XOR-swizzled (granule g' = g ^ (row&7)): SQ_LDS_BANK_CONFLICT=0.
// ---------------------------------------------------------------------------
__global__ __launch_bounds__(256) void gemm_kernel(
    const short* __restrict__ Cn, const short* __restrict__ vn,
    const float* __restrict__ wp, const float* __restrict__ bp,
    float* __restrict__ colsum)
{
    __shared__ short As[128 * 64];
    __shared__ short Bs[128 * 64];
    __shared__ float csum[128];

    const int tid  = threadIdx.x;
    const int wave = tid >> 6, lane = tid & 63;
    const int by = blockIdx.x;   // row tile: speakers    [0,16)   (fast-varying)
    const int bx = blockIdx.y;   // col tile: utterances  [0,256)
    const float wgt = *wp, bsc = *bp;

    if (tid < 128) csum[tid] = 0.f;   // first k-loop barrier makes this visible

    // staging: each wave stages 32 rows (4 issues x 8 rows x 16B/lane).
    // source column granule = (lane&7) ^ (row&7); row&7 == (lane>>3)&7.
    const int strow = wave * 32 + (lane >> 3);
    const int stcol = (((lane & 7) ^ ((lane >> 3) & 7))) * 8;
    const short* Abase = Cn + (size_t)(by * 128 + strow) * D_EMB + stcol;
    const short* Bbase = vn + (size_t)(bx * 128 + strow) * D_EMB + stcol;
    short* AsW = &As[(wave * 32) * 64];
    short* BsW = &Bs[(wave * 32) * 64];

    // compute geometry: 2x2 wave grid, each wave 64x64 = 4x4 MFMA tiles
    const int wm = wave & 1, wn = wave >> 1;
    const int l16 = lane & 15, quad = lane >> 4;
    const int rb = l16 & 7;
    const int go0 = (quad ^ rb) * 8;         // ks=0  granule offset (shorts)
    const int go1 = ((quad + 4) ^ rb) * 8;   // ks=32 granule offset
    const short* ArdBase = &As[(wm * 64 + l16) * 64];
    const short* BrdBase = &Bs[(wn * 64 + l16) * 64];

    f32x4 acc[4][4];
    const f32x4 z = {0.f, 0.f, 0.f, 0.f};
#pragma unroll
    for (int i = 0; i < 4; ++i)
#pragma unroll
        for (int j = 0; j < 4; ++j) acc[i][j] = z;

    for (int kk = 0; kk < D_EMB / 64; ++kk) {
        const int k0 = kk * 64;
        __syncthreads();
#pragma unroll
        for (int i = 0; i < 4; ++i) {
            async_copy16(Abase + (size_t)(i * 8) * D_EMB + k0, AsW + i * 8 * 64);
            async_copy16(Bbase + (size_t)(i * 8) * D_EMB + k0, BsW + i * 8 * 64);
        }
        __syncthreads();
#pragma unroll
        for (int ks = 0; ks < 2; ++ks) {
            const int go = ks ? go1 : go0;
            bf16x8 af[4], bfj[4];
#pragma unroll
            for (int i = 0; i < 4; ++i) af[i] = *(const bf16x8*)(ArdBase + i * 16 * 64 + go);
#pragma unroll
            for (int j = 0; j < 4; ++j) bfj[j] = *(const bf16x8*)(BrdBase + j * 16 * 64 + go);
#pragma unroll
            for (int i = 0; i < 4; ++i)
#pragma unroll
                for (int j = 0; j < 4; ++j)
                    acc[i][j] = __builtin_amdgcn_mfma_f32_16x16x32_bf16(
                        af[i], bfj[j], acc[i][j], 0, 0, 0);
        }
    }

    // epilogue: e = exp(w*S+b), zero same-speaker entries, reduce over rows.
    // D layout: row m = quad*4 + r (speaker), col n = l16 (utterance).
    const int rowg0 = by * 128 + wm * 64 + quad * 4;
    const int colg0 = bx * 128 + wn * 64 + l16;
#pragma unroll
    for (int j = 0; j < 4; ++j) {
        const int colg = colg0 + j * 16;
        const int cspk = colg >> 4;       // speaker owning this column
        float p = 0.f;
#pragma unroll
        for (int i = 0; i < 4; ++i) {
            const int rowg = rowg0 + i * 16;
#pragma unroll
            for (int r = 0; r < 4; ++r) {
                float e = __expf(wgt * acc[i][j][r] + bsc);
                p += (rowg + r == cspk) ? 0.f : e;
            }
        }
        p += __shfl_xor(p, 16);
        p += __shfl_xor(p, 32);
        if (quad == 0) atomicAdd(&csum[wn * 64 + j * 16 + l16], p);
    }
    __syncthreads();
    if (tid < 128) atomicAdd(&colsum[bx * 128 + tid], csum[tid]);
}

// ---------------------------------------------------------------------------
// Kernel C: L_j = -dterm_j + log(colsum_j + exp(dterm_j)); sum -> out[0]
// ---------------------------------------------------------------------------
__global__ __launch_bounds__(256) void finish_kernel(
    const float* __restrict__ dterm, const float* __restrict__ colsum,
    float* __restrict__ out)
{
    const int idx = blockIdx.x * 256 + threadIdx.x;
    const int stride = gridDim.x * 256;
    float local = 0.f;
    for (int j = idx; j < NM; j += stride) {
        float t = dterm[j];
        local += logf(colsum[j] + __expf(t)) - t;
    }
#pragma unroll
    for (int off = 32; off > 0; off >>= 1) local += __shfl_xor(local, off);
    __shared__ float wr[4];
    const int wave = threadIdx.x >> 6, lane = threadIdx.x & 63;
    if (lane == 0) wr[wave] = local;
    __syncthreads();
    if (threadIdx.x == 0) atomicAdd(out, wr[0] + wr[1] + wr[2] + wr[3]);
}

extern "C" void kernel_launch(void* const* d_in, const int* in_sizes, int n_in,
                              void* d_out, int out_size, void* d_ws, size_t ws_size,
                              hipStream_t stream) {
    const float* V  = (const float*)d_in[0];
    const float* wp = (const float*)d_in[1];
    const float* bp = (const float*)d_in[2];

    char*  ws     = (char*)d_ws;
    short* Cn     = (short*)ws;                              //  2 MB  [2048][512] bf16
    short* vn     = (short*)(ws + ((size_t)2 << 20));        // 32 MB  [32768][512] bf16
    float* dterm  = (float*)(ws + ((size_t)34 << 20));       // 128 KB [32768]
    float* colsum = dterm + NM;                              // 128 KB [32768]
    float* out    = (float*)d_out;

    prep_kernel<<<N_SPK, 128, 0, stream>>>(V, wp, bp, Cn, vn, dterm, colsum, out);
    gemm_kernel<<<dim3(N_SPK / 128, NM / 128), 256, 0, stream>>>(Cn, vn, wp, bp, colsum);
    finish_kernel<<<64, 256, 0, stream>>>(dterm, colsum, out);
}

// Round 4
// 153.141 us; speedup vs baseline: 1.3589x; 1.2094x over previous
//
#include <hip/hip_runtime.h>
#include <stdint.h>

#define N_SPK 2048
#define M_UTT 16
#define D_EMB 512
#define NM (N_SPK * M_UTT)
#define FP8_SCALE 16.0f   // quantization scale for fp8 operands (1/256 folded into w)

typedef __attribute__((ext_vector_type(4))) float f32x4;

__device__ __forceinline__ void async_copy16(const void* g, void* l) {
    __builtin_amdgcn_global_load_lds(
        (const __attribute__((address_space(1))) unsigned int*)g,
        (__attribute__((address_space(3))) unsigned int*)l,
        16, 0, 0);
}

// ---------------------------------------------------------------------------
// Kernel A: per-speaker prep. 256 thr/block, thread t owns dims {2t, 2t+1}
// (float2 x 16 rows = 32 VGPRs resident -- half of round 3, no spill risk).
// Single global pass; outputs fp8 e4m3 at x16 scale via v_cvt_pk_fp8_f32.
// dterm stays fp32-exact. Folds colsum/out zeroing.
// ---------------------------------------------------------------------------
__global__ __launch_bounds__(256) void prep_kernel(
    const float* __restrict__ V, const float* __restrict__ wp,
    const float* __restrict__ bp, unsigned char* __restrict__ Cn8,
    unsigned char* __restrict__ vn8, float* __restrict__ dterm,
    float* __restrict__ colsum, float* __restrict__ out)
{
    const int spk = blockIdx.x, t = threadIdx.x;
    const int wave = t >> 6, lane = t & 63;
    const float2* vb = (const float2*)(V + (size_t)spk * (M_UTT * D_EMB)); // [16][256]

    __shared__ __align__(16) float red[32][264];  // rows 0..15 sv, 16..31 vv (+8 pad)
    __shared__ float red2[32];
    __shared__ float invs[M_UTT];
    __shared__ float wred[4];

    // folded zeroing of colsum + out
    if (spk < 128) colsum[spk * 256 + t] = 0.f;
    if (spk == 0 && t == 0) out[0] = 0.f;

    // ---- single global read pass ----
    float2 p[M_UTT];
#pragma unroll
    for (int m = 0; m < M_UTT; ++m) p[m] = vb[m * 256 + t];

    float2 ss = make_float2(0.f, 0.f);
#pragma unroll
    for (int m = 0; m < M_UTT; ++m) { ss.x += p[m].x; ss.y += p[m].y; }

    // ||ssum||^2 butterfly (4 waves -> wred)
    float cnp = ss.x * ss.x + ss.y * ss.y;
#pragma unroll
    for (int off = 32; off > 0; off >>= 1) cnp += __shfl_xor(cnp, off);
    if (lane == 0) wred[wave] = cnp;

    // per-utterance partials -> LDS
#pragma unroll
    for (int m = 0; m < M_UTT; ++m) {
        red[m][t]         = ss.x * p[m].x + ss.y * p[m].y;          // <ssum, v> part
        red[m + M_UTT][t] = p[m].x * p[m].x + p[m].y * p[m].y;      // ||v||^2 part
    }
    __syncthreads();
    const float cn2 = wred[0] + wred[1] + wred[2] + wred[3];

    // ---- batched row reduction: 8 threads per row, 8 float4 each ----
    {
        const int r = t >> 3, s = t & 7;
        const float4* rp = (const float4*)red;   // row stride = 66 float4
        float4 a = make_float4(0.f, 0.f, 0.f, 0.f);
#pragma unroll
        for (int k = 0; k < 8; ++k) {
            float4 q = rp[r * 66 + s + 8 * k];
            a.x += q.x; a.y += q.y; a.z += q.z; a.w += q.w;
        }
        float v1 = (a.x + a.y) + (a.z + a.w);
        v1 += __shfl_xor(v1, 1);
        v1 += __shfl_xor(v1, 2);
        v1 += __shfl_xor(v1, 4);
        if (s == 0) red2[r] = v1;
    }
    __syncthreads();

    // ---- per-utterance scalars (fp32-exact leave-one-out sims) ----
    if (t < M_UTT) {
        const float sv = red2[t], vv = red2[t + M_UTT];
        const float cc = cn2 - 2.f * sv + vv;      // ||ssum - v||^2
        const float cv = sv - vv;                  // <ssum - v, v>
        const float dc = fmaxf(sqrtf(fmaxf(cc, 0.f)) * (1.f / (M_UTT - 1)), 1e-8f) * (M_UTT - 1);
        const float dv = fmaxf(sqrtf(vv), 1e-8f);
        dterm[spk * M_UTT + t] = (*wp) * (cv / (dc * dv)) + (*bp);
        invs[t] = FP8_SCALE / dv;
    }
    __syncthreads();

    // ---- fp8 outputs (x16 scale) ----
    const float cs = FP8_SCALE / (M_UTT * fmaxf(sqrtf(cn2) * (1.f / M_UTT), 1e-8f));
    {
        int pk = __builtin_amdgcn_cvt_pk_fp8_f32(ss.x * cs, ss.y * cs, 0, false);
        ((unsigned short*)(Cn8 + (size_t)spk * D_EMB))[t] = (unsigned short)pk;
    }
#pragma unroll
    for (int m = 0; m < M_UTT; ++m) {
        const float iv = invs[m];
        int pk = __builtin_amdgcn_cvt_pk_fp8_f32(p[m].x * iv, p[m].y * iv, 0, false);
        ((unsigned short*)(vn8 + ((size_t)(spk * M_UTT + m)) * D_EMB))[t] = (unsigned short)pk;
    }
}

// ---------------------------------------------------------------------------
// Kernel B: fp8 GEMM. S = Cn8 @ vn8^T (x256 scale) fused with exp(w'S+b),
// same-speaker masking, column reduction. 128x128 tile, BK=64,
// mfma_f32_16x16x32_fp8_fp8 (MFMA-bound: 16 ds_read_b64 ~96cyc vs 32 MFMA
// ~155cyc per K-step per wave -- bf16's 16 b128 ~192cyc bound removed).
// Swizzle: LDS 16B slot j of row r holds global slot j ^ s(r),
// s(r) = (r&3)^((r>>2)&3); b64 fragment reads land uniformly 4 lanes/bank
// (= the b64 throughput floor, no excess conflict).
// ---------------------------------------------------------------------------
__global__ __launch_bounds__(256) void gemm_kernel(
    const unsigned char* __restrict__ Cn8, const unsigned char* __restrict__ vn8,
    const float* __restrict__ wp, const float* __restrict__ bp,
    float* __restrict__ colsum)
{
    __shared__ __align__(16) unsigned char As[128 * 64];
    __shared__ __align__(16) unsigned char Bs[128 * 64];
    __shared__ float csum[128];

    const int tid = threadIdx.x;
    const int w = tid >> 6, l = tid & 63;
    const int by = blockIdx.x;   // speaker tiles   [0,16)  (fast-varying)
    const int bx = blockIdx.y;   // utterance tiles [0,256)
    const float wgt = (*wp) * (1.f / (FP8_SCALE * FP8_SCALE));
    const float bsc = *bp;

    if (tid < 128) csum[tid] = 0.f;

    // staging: 2 issues/matrix/kk; issue i covers rows w*32 + i*16 + (l>>2).
    // LDS slot (l&3) must hold global slot (l&3) ^ s(row); s(row) reduces to
    // ((l>>2)^(l>>4))&3 for both issues.
    const int srow = w * 32 + (l >> 2);
    const int sj   = ((l & 3) ^ ((l >> 2) ^ (l >> 4))) & 3;
    const unsigned char* Ab = Cn8 + (size_t)(by * 128 + srow) * D_EMB + sj * 16;
    const unsigned char* Bb = vn8 + (size_t)(bx * 128 + srow) * D_EMB + sj * 16;
    unsigned char* AsW = As + w * 2048;
    unsigned char* BsW = Bs + w * 2048;

    // compute geometry: 2x2 wave grid, each wave 64x64 = 4x4 MFMA tiles
    const int wm = w & 1, wn = w >> 1;
    const int l16 = l & 15, q = l >> 4;
    const int sl = (l16 ^ (l16 >> 2)) & 3;
    const int off0 = (((q >> 1)    ) ^ sl) * 16 + (q & 1) * 8;  // k-half 0 (chunk q)
    const int off1 = (((q >> 1) + 2) ^ sl) * 16 + (q & 1) * 8;  // k-half 1 (chunk q+4)
    const unsigned char* Ard = As + (wm * 64 + l16) * 64;
    const unsigned char* Brd = Bs + (wn * 64 + l16) * 64;

    f32x4 acc[4][4];
    const f32x4 z = {0.f, 0.f, 0.f, 0.f};
#pragma unroll
    for (int i = 0; i < 4; ++i)
#pragma unroll
        for (int j = 0; j < 4; ++j) acc[i][j] = z;

    for (int kk = 0; kk < D_EMB; kk += 64) {
        __syncthreads();
        async_copy16(Ab + kk, AsW);
        async_copy16(Ab + 16 * D_EMB + kk, AsW + 1024);
        async_copy16(Bb + kk, BsW);
        async_copy16(Bb + 16 * D_EMB + kk, BsW + 1024);
        __syncthreads();
#pragma unroll
        for (int h = 0; h < 2; ++h) {
            const int off = h ? off1 : off0;
            long af[4], bfr[4];
#pragma unroll
            for (int i = 0; i < 4; ++i) af[i] = *(const long*)(Ard + i * 16 * 64 + off);
#pragma unroll
            for (int j = 0; j < 4; ++j) bfr[j] = *(const long*)(Brd + j * 16 * 64 + off);
#pragma unroll
            for (int i = 0; i < 4; ++i)
#pragma unroll
                for (int j = 0; j < 4; ++j)
                    acc[i][j] = __builtin_amdgcn_mfma_f32_16x16x32_fp8_fp8(
                        af[i], bfr[j], acc[i][j], 0, 0, 0);
        }
    }

    // epilogue: e = exp(w'*dot+b), zero same-speaker entries, reduce over rows.
    // C/D layout (shape-determined, dtype-independent): row = quad*4+r, col = l16.
    const int rowg0 = by * 128 + wm * 64 + q * 4;
    const int colg0 = bx * 128 + wn * 64 + l16;
#pragma unroll
    for (int j = 0; j < 4; ++j) {
        const int colg = colg0 + j * 16;
        const int cspk = colg >> 4;       // speaker owning this column
        float p = 0.f;
#pragma unroll
        for (int i = 0; i < 4; ++i) {
            const int rowg = rowg0 + i * 16;
#pragma unroll
            for (int r = 0; r < 4; ++r) {
                float e = __expf(wgt * acc[i][j][r] + bsc);
                p += (rowg + r == cspk) ? 0.f : e;
            }
        }
        p += __shfl_xor(p, 16);
        p += __shfl_xor(p, 32);
        if (q == 0) atomicAdd(&csum[wn * 64 + j * 16 + l16], p);
    }
    __syncthreads();
    if (tid < 128) atomicAdd(&colsum[bx * 128 + tid], csum[tid]);
}

// ---------------------------------------------------------------------------
// Kernel C: L_j = -dterm_j + log(colsum_j + exp(dterm_j)); sum -> out[0]
// ---------------------------------------------------------------------------
__global__ __launch_bounds__(256) void finish_kernel(
    const float* __restrict__ dterm, const float* __restrict__ colsum,
    float* __restrict__ out)
{
    const int idx = blockIdx.x * 256 + threadIdx.x;
    const int stride = gridDim.x * 256;
    float local = 0.f;
    for (int j = idx; j < NM; j += stride) {
        float t = dterm[j];
        local += logf(colsum[j] + __expf(t)) - t;
    }
#pragma unroll
    for (int off = 32; off > 0; off >>= 1) local += __shfl_xor(local, off);
    __shared__ float wr[4];
    const int wave = threadIdx.x >> 6, lane = threadIdx.x & 63;
    if (lane == 0) wr[wave] = local;
    __syncthreads();
    if (threadIdx.x == 0) atomicAdd(out, wr[0] + wr[1] + wr[2] + wr[3]);
}

extern "C" void kernel_launch(void* const* d_in, const int* in_sizes, int n_in,
                              void* d_out, int out_size, void* d_ws, size_t ws_size,
                              hipStream_t stream) {
    const float* V  = (const float*)d_in[0];
    const float* wp = (const float*)d_in[1];
    const float* bp = (const float*)d_in[2];

    char* ws = (char*)d_ws;
    unsigned char* Cn8 = (unsigned char*)ws;                        //  1 MB [2048][512] fp8
    unsigned char* vn8 = (unsigned char*)(ws + ((size_t)1 << 20));  // 16 MB [32768][512] fp8
    float* dterm  = (float*)(ws + ((size_t)17 << 20));              // 128 KB
    float* colsum = dterm + NM;                                     // 128 KB
    float* out    = (float*)d_out;

    prep_kernel<<<N_SPK, 256, 0, stream>>>(V, wp, bp, Cn8, vn8, dterm, colsum, out);
    gemm_kernel<<<dim3(N_SPK / 128, NM / 128), 256, 0, stream>>>(Cn8, vn8, wp, bp, colsum);
    finish_kernel<<<64, 256, 0, stream>>>(dterm, colsum, out);
}